// Round 7
// baseline (242.357 us; speedup 1.0000x reference)
//
#include <hip/hip_runtime.h>
#include <math.h>

// Reverse cumulative max (suffix max) along last dim.
// x: (8,1,2048,2048) fp32 -> 16384 rows of W=2048.
//
// Round 7: the {load,store}x{alloc,NT} matrix showed store policy is NULL
// and only the load path matters (alloc=81us, NT=~70us kernel). The wall is
// the read stream running at ~<4 TB/s whenever it shares the kernel window
// with the write stream (fill proves write-only does 6.6 TB/s). Untested
// regime: separate the streams IN TIME, device-wide, via a two-pass split
// with Infinity Cache as the row buffer:
//   Pass A (pure read): alloc-load rows -> MALL-resident; reduce each row to
//     8 cross-chunk suffix tails; write 32B/row to workspace (512 KiB).
//   Pass B (MALL read + pure HBM write): re-read rows (MALL hits), do the
//     within-chunk scan, fold with precomputed tails, NT-store output.
// Tells: B's FETCH_SIZE << 128 MiB (MALL retention), A < 35us (pure-read
// rate). If A >= 40us, alloc-reads are intrinsically capped -> roofline.

#define ROW_W 2048
#define LANES 64
#define CHUNKS 8               // float4 per lane per row (8*64*4 = 2048)
#define WAVES_PER_BLOCK 4

typedef float nf4 __attribute__((ext_vector_type(4)));

// ---------- Pass A: per-row cross-chunk suffix tails ----------
__global__ __launch_bounds__(256) void row_tails_kernel(
    const float* __restrict__ x, float* __restrict__ aux, int nrows) {
  const int lane = threadIdx.x & 63;
  const int row  = blockIdx.x * WAVES_PER_BLOCK + (threadIdx.x >> 6);
  if (row >= nrows) return;

  const nf4* __restrict__ p = (const nf4*)(x + (size_t)row * ROW_W) + lane;
  // Allocating loads: park the row in the Infinity Cache for pass B.
  float m[CHUNKS];
#pragma unroll
  for (int k = 0; k < CHUNKS; ++k) {
    nf4 v = p[k * LANES];
    m[k] = fmaxf(fmaxf(v.x, v.y), fmaxf(v.z, v.w));
  }
  // Cross-lane max per chunk (8 independent 64-lane reductions).
#pragma unroll
  for (int off = 1; off < LANES; off <<= 1) {
#pragma unroll
    for (int k = 0; k < CHUNKS; ++k)
      m[k] = fmaxf(m[k], __shfl_down(m[k], off, LANES));
  }
  // Lane 0 holds tot[k] = max of chunk k. Fold to exclusive suffix tails.
  if (lane == 0) {
    float tails[CHUNKS];
    float t = -INFINITY;
#pragma unroll
    for (int k = CHUNKS - 1; k >= 0; --k) {
      tails[k] = t;
      t = fmaxf(t, m[k]);
    }
    nf4 t0 = {tails[0], tails[1], tails[2], tails[3]};
    nf4 t1 = {tails[4], tails[5], tails[6], tails[7]};
    nf4* q = (nf4*)(aux + (size_t)row * CHUNKS);
    q[0] = t0;
    q[1] = t1;
  }
}

// ---------- Pass B: within-chunk scan + tail fold, NT output ----------
__global__ __launch_bounds__(256) void suffix_apply_kernel(
    const float* __restrict__ x, const float* __restrict__ aux,
    float* __restrict__ out, int nrows) {
  const int lane = threadIdx.x & 63;
  const int row  = blockIdx.x * WAVES_PER_BLOCK + (threadIdx.x >> 6);
  if (row >= nrows) return;

  const nf4* __restrict__ p = (const nf4*)(x   + (size_t)row * ROW_W) + lane;
  nf4* __restrict__       q = (nf4*)      (out + (size_t)row * ROW_W) + lane;

  // Plain loads: should hit MALL (row parked there by pass A).
  nf4 v[CHUNKS];
#pragma unroll
  for (int k = 0; k < CHUNKS; ++k) v[k] = p[k * LANES];

  // Wave-uniform tail load (all lanes same address -> broadcast).
  const nf4* __restrict__ ta = (const nf4*)(aux + (size_t)row * CHUNKS);
  const nf4 t0 = ta[0], t1 = ta[1];
  const float tail[CHUNKS] = {t0.x, t0.y, t0.z, t0.w, t1.x, t1.y, t1.z, t1.w};

  // 1) Suffix max inside each float4 (right-to-left).
  float inc[CHUNKS];
#pragma unroll
  for (int k = 0; k < CHUNKS; ++k) {
    v[k].z = fmaxf(v[k].z, v[k].w);
    v[k].y = fmaxf(v[k].y, v[k].z);
    v[k].x = fmaxf(v[k].x, v[k].y);
    inc[k] = v[k].x;
  }
  // 2) Eight independent 64-lane suffix scans (fmaxf idempotent -> no guards).
#pragma unroll
  for (int off = 1; off < LANES; off <<= 1) {
#pragma unroll
    for (int k = 0; k < CHUNKS; ++k) {
      float o = __shfl_down(inc[k], off, LANES);
      inc[k] = fmaxf(inc[k], o);
    }
  }
  float excl[CHUNKS];
#pragma unroll
  for (int k = 0; k < CHUNKS; ++k) {
    float e = __shfl_down(inc[k], 1, LANES);
    excl[k] = (lane == 63) ? -INFINITY : e;
  }
  // 3) Fold: right-neighbor-within-chunk vs precomputed cross-chunk tail.
  //    (No serial cross-chunk chain anymore.)
#pragma unroll
  for (int k = 0; k < CHUNKS; ++k) {
    const float e = fmaxf(excl[k], tail[k]);
    v[k].x = fmaxf(v[k].x, e);
    v[k].y = fmaxf(v[k].y, e);
    v[k].z = fmaxf(v[k].z, e);
    v[k].w = fmaxf(v[k].w, e);
  }
  // Nontemporal coalesced stores: pure HBM write stream, no MALL eviction.
#pragma unroll
  for (int k = 0; k < CHUNKS; ++k)
    __builtin_nontemporal_store(v[k], &q[k * LANES]);
}

// ---------- Fallback single-pass (R4 config) if workspace too small ----------
__global__ __launch_bounds__(256) void suffix_max_single(
    const float* __restrict__ x, float* __restrict__ out, int nrows) {
  const int lane = threadIdx.x & 63;
  const int row  = blockIdx.x * WAVES_PER_BLOCK + (threadIdx.x >> 6);
  if (row >= nrows) return;
  const nf4* __restrict__ p = (const nf4*)(x   + (size_t)row * ROW_W) + lane;
  nf4* __restrict__       q = (nf4*)      (out + (size_t)row * ROW_W) + lane;
  nf4 v[CHUNKS];
#pragma unroll
  for (int k = 0; k < CHUNKS; ++k)
    v[k] = __builtin_nontemporal_load(&p[k * LANES]);
  float inc[CHUNKS];
#pragma unroll
  for (int k = 0; k < CHUNKS; ++k) {
    v[k].z = fmaxf(v[k].z, v[k].w);
    v[k].y = fmaxf(v[k].y, v[k].z);
    v[k].x = fmaxf(v[k].x, v[k].y);
    inc[k] = v[k].x;
  }
#pragma unroll
  for (int off = 1; off < LANES; off <<= 1) {
#pragma unroll
    for (int k = 0; k < CHUNKS; ++k) {
      float o = __shfl_down(inc[k], off, LANES);
      inc[k] = fmaxf(inc[k], o);
    }
  }
  float tot[CHUNKS], excl[CHUNKS];
#pragma unroll
  for (int k = 0; k < CHUNKS; ++k) tot[k] = __shfl(inc[k], 0, LANES);
#pragma unroll
  for (int k = 0; k < CHUNKS; ++k) {
    float e = __shfl_down(inc[k], 1, LANES);
    excl[k] = (lane == 63) ? -INFINITY : e;
  }
  float tail = -INFINITY;
#pragma unroll
  for (int k = CHUNKS - 1; k >= 0; --k) {
    const float e = fmaxf(excl[k], tail);
    v[k].x = fmaxf(v[k].x, e);
    v[k].y = fmaxf(v[k].y, e);
    v[k].z = fmaxf(v[k].z, e);
    v[k].w = fmaxf(v[k].w, e);
    tail = fmaxf(tail, tot[k]);
  }
#pragma unroll
  for (int k = 0; k < CHUNKS; ++k)
    __builtin_nontemporal_store(v[k], &q[k * LANES]);
}

extern "C" void kernel_launch(void* const* d_in, const int* in_sizes, int n_in,
                              void* d_out, int out_size, void* d_ws, size_t ws_size,
                              hipStream_t stream) {
  const float* x = (const float*)d_in[0];
  float* out = (float*)d_out;
  const int nrows = out_size / ROW_W;  // 16384
  const int blocks = (nrows + WAVES_PER_BLOCK - 1) / WAVES_PER_BLOCK;
  const size_t aux_bytes = (size_t)nrows * CHUNKS * sizeof(float);  // 512 KiB

  if (d_ws != nullptr && ws_size >= aux_bytes) {
    float* aux = (float*)d_ws;
    row_tails_kernel<<<blocks, 256, 0, stream>>>(x, aux, nrows);
    suffix_apply_kernel<<<blocks, 256, 0, stream>>>(x, aux, out, nrows);
  } else {
    suffix_max_single<<<blocks, 256, 0, stream>>>(x, out, nrows);
  }
}

// Round 8
// 218.403 us; speedup vs baseline: 1.1097x; 1.1097x over previous
//
#include <hip/hip_runtime.h>
#include <math.h>

// Reverse cumulative max (suffix max) along last dim.
// x: (8,1,2048,2048) fp32 -> 16384 rows of W=2048. One wave per row.
//
// Round 8: ledger so far — store cache-policy NULL, occupancy NULL (29-60%),
// addressing NULL (x3), burst pipelining NULL (depth 2/4), two-pass stream
// separation NEGATIVE (+22us), NT loads +14% (only live lever). Best = R4
// (NT/NT one-shot, ~60-70us, ~4 TB/s combined) vs m13 copy anchor 6.29 TB/s
// combined. The one structural difference from a copy kernel is the per-wave
// schedule: copy = load;store;load;store continuous; ours = 8-load burst ->
// drain -> 500cy shuffle chain -> 8-store burst. This round samples the
// copy-shaped regime: process the row right-to-left, one 1-KiB chunk per
// step, carrying the running suffix max; per step {issue load k-2 | scan
// chunk k | store chunk k}, pinned with sched_barrier(0) so hipcc cannot
// hoist the loads back into one burst. 2 loads + 1 store in flight through
// every scan; 1:1 load/store interleave at 1 KiB grain.
// Predict: kernel ~45-52us, e2e ~200-208. If e2e ~220 (null): roofline.

#define ROW_W 2048
#define LANES 64
#define WAVES_PER_BLOCK 4

typedef float nf4 __attribute__((ext_vector_type(4)));

__global__ __launch_bounds__(256) void suffix_max_kernel(
    const float* __restrict__ x, float* __restrict__ out, int nrows) {
  const int lane = threadIdx.x & 63;
  const int row  = blockIdx.x * WAVES_PER_BLOCK + (threadIdx.x >> 6);
  if (row >= nrows) return;

  const nf4* __restrict__ p = (const nf4*)(x   + (size_t)row * ROW_W) + lane;
  nf4* __restrict__       q = (nf4*)      (out + (size_t)row * ROW_W) + lane;

  float carry = -INFINITY;  // suffix max of all chunks to the right

  // Scan one 256-float chunk (lane-strided: lane l holds float4 #l) with
  // the running carry, NT-store it, update carry. ~8 cross-lane ops.
  auto scan_store = [&](nf4 v, int k) {
    // suffix max inside the float4 (right-to-left)
    v.z = fmaxf(v.z, v.w);
    v.y = fmaxf(v.y, v.z);
    v.x = fmaxf(v.x, v.y);
    // 64-lane inclusive suffix scan of per-lane maxes
    float inc = v.x;
#pragma unroll
    for (int off = 1; off < LANES; off <<= 1) {
      float o = __shfl_down(inc, off, LANES);   // self-return past end: ok
      inc = fmaxf(inc, o);
    }
    float excl = __shfl_down(inc, 1, LANES);
    if (lane == 63) excl = -INFINITY;
    const float tot = __shfl(inc, 0, LANES);    // whole-chunk max
    const float e = fmaxf(excl, carry);
    v.x = fmaxf(v.x, e);
    v.y = fmaxf(v.y, e);
    v.z = fmaxf(v.z, e);
    v.w = fmaxf(v.w, e);
    __builtin_nontemporal_store(v, &q[k * LANES]);
    carry = fmaxf(carry, tot);
  };

  // Copy-shaped pipeline, right to left, 2-chunk load lookahead.
  nf4 c7 = __builtin_nontemporal_load(&p[7 * LANES]);
  nf4 c6 = __builtin_nontemporal_load(&p[6 * LANES]);
  __builtin_amdgcn_sched_barrier(0);

  nf4 c5 = __builtin_nontemporal_load(&p[5 * LANES]);
  scan_store(c7, 7);
  __builtin_amdgcn_sched_barrier(0);

  nf4 c4 = __builtin_nontemporal_load(&p[4 * LANES]);
  scan_store(c6, 6);
  __builtin_amdgcn_sched_barrier(0);

  nf4 c3 = __builtin_nontemporal_load(&p[3 * LANES]);
  scan_store(c5, 5);
  __builtin_amdgcn_sched_barrier(0);

  nf4 c2 = __builtin_nontemporal_load(&p[2 * LANES]);
  scan_store(c4, 4);
  __builtin_amdgcn_sched_barrier(0);

  nf4 c1 = __builtin_nontemporal_load(&p[1 * LANES]);
  scan_store(c3, 3);
  __builtin_amdgcn_sched_barrier(0);

  nf4 c0 = __builtin_nontemporal_load(&p[0 * LANES]);
  scan_store(c2, 2);
  __builtin_amdgcn_sched_barrier(0);

  scan_store(c1, 1);
  scan_store(c0, 0);
}

extern "C" void kernel_launch(void* const* d_in, const int* in_sizes, int n_in,
                              void* d_out, int out_size, void* d_ws, size_t ws_size,
                              hipStream_t stream) {
  const float* x = (const float*)d_in[0];
  float* out = (float*)d_out;
  const int nrows = out_size / ROW_W;  // 16384
  const int blocks = (nrows + WAVES_PER_BLOCK - 1) / WAVES_PER_BLOCK;
  suffix_max_kernel<<<blocks, 256, 0, stream>>>(x, out, nrows);
}